// Round 1
// baseline (437.425 us; speedup 1.0000x reference)
//
#include <hip/hip_runtime.h>
#include <hip/hip_bf16.h>

// GCNConv forward: out = D^-1/2 (A+I) D^-1/2 (x W^T) + b
// N=100000, E=1600000, DIM=128. fp32 in/out, edge_index as int32.
//
// Pipeline (all on `stream`, graph-capture safe):
//   1. zero_deg          : deg[] = 0
//   2. fill_buckets      : per-edge: p=atomicAdd(deg[dst]); bucket[dst*CAP+p]=src
//   3. compute_dinv      : dinv[n] = rsqrt(deg[n]+1)   (+1 = self loop)
//   4. gemm_xWt          : x_lin = x @ W.T  (fp32 tiled, W^T staged in LDS)
//   5. aggregate         : out[n] = dinv[n]*(dinv[n]*xlin[n] + sum_s dinv[s]*xlin[s]) + b

#define DIM 128
#define CAP 64   // max in-degree bucket capacity; E/N=16 avg, Poisson tail @64 ~ 1e-20

__global__ __launch_bounds__(256) void zero_deg(int* __restrict__ deg, int n) {
    int i = blockIdx.x * 256 + threadIdx.x;
    if (i < n) deg[i] = 0;
}

__global__ __launch_bounds__(256) void fill_buckets(const int* __restrict__ ei, int E,
                                                    int* __restrict__ deg,
                                                    int* __restrict__ bucket) {
    int e = blockIdx.x * 256 + threadIdx.x;
    if (e >= E) return;
    int s = ei[e];        // src row
    int d = ei[E + e];    // dst row
    int p = atomicAdd(&deg[d], 1);
    if (p < CAP) bucket[d * CAP + p] = s;
}

__global__ __launch_bounds__(256) void compute_dinv(const int* __restrict__ deg,
                                                    float* __restrict__ dinv, int n) {
    int i = blockIdx.x * 256 + threadIdx.x;
    if (i < n) dinv[i] = rsqrtf((float)(deg[i] + 1));  // +1 self loop, always > 0
}

// x_lin[n][j] = sum_k x[n][k] * W[j][k].
// Block: 256 threads, 32 rows of x, all 128 cols. W^T staged in LDS as wt[k][c]
// (row stride 132 floats keeps float4 reads 16B-aligned; bank spread ~4-way).
__global__ __launch_bounds__(256) void gemm_xWt(const float* __restrict__ x,
                                                const float* __restrict__ W,
                                                float* __restrict__ xlin) {
    __shared__ float wt[DIM][132];  // wt[k][c] = W[c][k]
    int t = threadIdx.x;
    // stage W transposed: 4096 float4 chunks of W, 16 per thread
    for (int it = 0; it < 16; ++it) {
        int f = it * 256 + t;       // float4 index into W
        int c = f >> 5;             // W row (output col), 0..127
        int kq = f & 31;            // k quad, 0..31
        float4 w4 = ((const float4*)W)[f];
        wt[kq * 4 + 0][c] = w4.x;
        wt[kq * 4 + 1][c] = w4.y;
        wt[kq * 4 + 2][c] = w4.z;
        wt[kq * 4 + 3][c] = w4.w;
    }
    __syncthreads();

    int tc = t & 31;                // 32 col-groups of 4
    int tr = t >> 5;                // 8 row-groups of 4
    int c0 = tc * 4;
    int r0 = blockIdx.x * 32 + tr * 4;   // 100000/32 = 3125 blocks exactly
    const float* xr = x + r0 * DIM;

    float acc[4][4] = {};
    for (int k4 = 0; k4 < DIM; k4 += 4) {
        float av[4][4], wv[4][4];
#pragma unroll
        for (int i = 0; i < 4; ++i) {
            float4 a = *(const float4*)(xr + i * DIM + k4);  // broadcast within wave
            av[i][0] = a.x; av[i][1] = a.y; av[i][2] = a.z; av[i][3] = a.w;
        }
#pragma unroll
        for (int kk = 0; kk < 4; ++kk) {
            float4 w = *(const float4*)(&wt[k4 + kk][c0]);
            wv[kk][0] = w.x; wv[kk][1] = w.y; wv[kk][2] = w.z; wv[kk][3] = w.w;
        }
#pragma unroll
        for (int i = 0; i < 4; ++i)
#pragma unroll
            for (int kk = 0; kk < 4; ++kk)
#pragma unroll
                for (int j = 0; j < 4; ++j)
                    acc[i][j] = fmaf(av[i][kk], wv[kk][j], acc[i][j]);
    }
#pragma unroll
    for (int i = 0; i < 4; ++i) {
        float4 o = make_float4(acc[i][0], acc[i][1], acc[i][2], acc[i][3]);
        *(float4*)(xlin + (r0 + i) * DIM + c0) = o;
    }
}

// 32 lanes per node, each owns 4 feature dims (float4). 8 nodes per 256-block.
__global__ __launch_bounds__(256) void aggregate(const float* __restrict__ xlin,
                                                 const int* __restrict__ bucket,
                                                 const int* __restrict__ deg,
                                                 const float* __restrict__ dinv,
                                                 const float* __restrict__ bias,
                                                 float* __restrict__ out, int N) {
    int node = blockIdx.x * 8 + (threadIdx.x >> 5);
    int lane = threadIdx.x & 31;
    if (node >= N) return;

    float di = dinv[node];
    int cnt = deg[node];
    if (cnt > CAP) cnt = CAP;

    const float4* xl4 = (const float4*)xlin;
    float4 a = xl4[node * 32 + lane];            // self-loop message
    float4 acc = make_float4(di * a.x, di * a.y, di * a.z, di * a.w);

    const int* cl = bucket + node * CAP;
    for (int i = 0; i < cnt; ++i) {
        int s = cl[i];                           // broadcast across 32 lanes
        float ds = dinv[s];
        float4 v = xl4[s * 32 + lane];           // 512B coalesced row segment
        acc.x = fmaf(ds, v.x, acc.x);
        acc.y = fmaf(ds, v.y, acc.y);
        acc.z = fmaf(ds, v.z, acc.z);
        acc.w = fmaf(ds, v.w, acc.w);
    }

    float4 bb = ((const float4*)bias)[lane];
    float4 o = make_float4(di * acc.x + bb.x, di * acc.y + bb.y,
                           di * acc.z + bb.z, di * acc.w + bb.w);
    ((float4*)out)[node * 32 + lane] = o;
}

extern "C" void kernel_launch(void* const* d_in, const int* in_sizes, int n_in,
                              void* d_out, int out_size, void* d_ws, size_t ws_size,
                              hipStream_t stream) {
    const float* x    = (const float*)d_in[0];
    const int*   ei   = (const int*)d_in[1];
    const float* W    = (const float*)d_in[2];
    const float* bias = (const float*)d_in[3];
    float* out = (float*)d_out;

    const int N = in_sizes[0] / DIM;      // 100000
    const int E = in_sizes[1] / 2;        // 1600000

    // workspace layout (bytes): xlin | deg | dinv | bucket
    char* ws = (char*)d_ws;
    float* xlin  = (float*)(ws);                                   // N*128*4 = 51.2 MB
    int*   deg   = (int*)  (ws + (size_t)N * DIM * 4);             // N*4
    float* dinv  = (float*)(ws + (size_t)N * DIM * 4 + (size_t)N * 4);
    int*   bucket= (int*)  (ws + (size_t)N * DIM * 4 + (size_t)N * 8);  // N*CAP*4 = 25.6 MB

    zero_deg<<<(N + 255) / 256, 256, 0, stream>>>(deg, N);
    fill_buckets<<<(E + 255) / 256, 256, 0, stream>>>(ei, E, deg, bucket);
    compute_dinv<<<(N + 255) / 256, 256, 0, stream>>>(deg, dinv, N);
    gemm_xWt<<<N / 32, 256, 0, stream>>>(x, W, xlin);
    aggregate<<<(N + 7) / 8, 256, 0, stream>>>(xlin, bucket, deg, dinv, bias, out, N);
}

// Round 2
// 345.232 us; speedup vs baseline: 1.2670x; 1.2670x over previous
//
#include <hip/hip_runtime.h>
#include <hip/hip_bf16.h>

// GCNConv forward: out = D^-1/2 (A+I) D^-1/2 (x W^T) + b
// N=100000, E=1600000, DIM=128. fp32 in/out, edge_index as int32.
//
// R2: xlin stored bf16 (halves gather traffic), GEMM via bf16 MFMA.

#define DIM 128
#define CAP 64        // max in-degree bucket capacity; Poisson(16) tail @64 ~1e-20
#define WSTRIDE 136   // shorts per LDS row: 272B = 17*16B -> 16B-aligned b128, 2-way banks

typedef __attribute__((ext_vector_type(8))) short short8;
typedef __attribute__((ext_vector_type(4))) float f32x4;

__device__ inline unsigned short f2bf(float f) {
    unsigned u = __builtin_bit_cast(unsigned, f);
    return (unsigned short)((u + 0x7FFFu + ((u >> 16) & 1u)) >> 16);
}

__global__ __launch_bounds__(256) void zero_deg(int* __restrict__ deg, int n) {
    int i = blockIdx.x * 256 + threadIdx.x;
    if (i < n) deg[i] = 0;
}

__global__ __launch_bounds__(256) void fill_buckets(const int* __restrict__ ei, int E,
                                                    int* __restrict__ deg,
                                                    int* __restrict__ bucket) {
    int e = blockIdx.x * 256 + threadIdx.x;
    if (e >= E) return;
    int s = ei[e];        // src
    int d = ei[E + e];    // dst
    int p = atomicAdd(&deg[d], 1);
    if (p < CAP) bucket[d * CAP + p] = s;
}

__global__ __launch_bounds__(256) void compute_dinv(const int* __restrict__ deg,
                                                    float* __restrict__ dinv, int n) {
    int i = blockIdx.x * 256 + threadIdx.x;
    if (i < n) dinv[i] = rsqrtf((float)(deg[i] + 1));  // +1 self loop
}

// xlin[n][j] = sum_k x[n][k] * W[j][k], output bf16.
// Block 256 = 4 waves; wave computes 16 rows x 128 cols via 16x16x32 MFMA.
// A frag: A[m=lane&15][k=quad*8+i]; B frag: B[k=quad*8+i][n=lane&15] = W[jt*16+(lane&15)][k].
// C/D: col=lane&15, row=quad*4+reg -> transpose via per-wave LDS for coalesced stores.
__global__ __launch_bounds__(256) void gemm_mfma(const float* __restrict__ x,
                                                 const float* __restrict__ W,
                                                 unsigned short* __restrict__ xlin, int N) {
    __shared__ unsigned short wbf[DIM * WSTRIDE];       // W as bf16, [j][k], 34.8 KB
    __shared__ unsigned short obuf[4 * 16 * WSTRIDE];   // per-wave 16x128 out tile, 17.4 KB
    int t = threadIdx.x;

    // stage W -> bf16 LDS (coalesced float4 reads of all 64 KB)
    for (int it = 0; it < 16; ++it) {
        int f = it * 256 + t;           // float4 index, 4096 total
        int j = f >> 5;                 // W row (output col) 0..127
        int kq = f & 31;                // k quad
        float4 w4 = ((const float4*)W)[f];
        unsigned short* p = &wbf[j * WSTRIDE + kq * 4];
        p[0] = f2bf(w4.x); p[1] = f2bf(w4.y); p[2] = f2bf(w4.z); p[3] = f2bf(w4.w);
    }
    __syncthreads();

    int wid = t >> 6, lane = t & 63;
    int m = lane & 15, quad = lane >> 4;
    int row_base = blockIdx.x * 64 + wid * 16;

    f32x4 acc[8];
#pragma unroll
    for (int j = 0; j < 8; ++j) acc[j] = (f32x4){0.f, 0.f, 0.f, 0.f};

    int arow = row_base + m;
    if (arow >= N) arow = N - 1;        // clamp (store is guarded)
    const float* xr = x + (size_t)arow * DIM + quad * 8;

#pragma unroll
    for (int kc = 0; kc < 4; ++kc) {
        float4 a0 = *(const float4*)(xr + kc * 32);
        float4 a1 = *(const float4*)(xr + kc * 32 + 4);
        short8 af;
        af[0] = (short)f2bf(a0.x); af[1] = (short)f2bf(a0.y);
        af[2] = (short)f2bf(a0.z); af[3] = (short)f2bf(a0.w);
        af[4] = (short)f2bf(a1.x); af[5] = (short)f2bf(a1.y);
        af[6] = (short)f2bf(a1.z); af[7] = (short)f2bf(a1.w);
#pragma unroll
        for (int jt = 0; jt < 8; ++jt) {
            short8 bf = *(const short8*)&wbf[(jt * 16 + m) * WSTRIDE + kc * 32 + quad * 8];
            acc[jt] = __builtin_amdgcn_mfma_f32_16x16x32_bf16(af, bf, acc[jt], 0, 0, 0);
        }
    }

    // epilogue: C layout -> LDS -> coalesced 16B global stores
    unsigned short* ob = &obuf[wid * 16 * WSTRIDE];
#pragma unroll
    for (int jt = 0; jt < 8; ++jt)
#pragma unroll
        for (int r = 0; r < 4; ++r)
            ob[(quad * 4 + r) * WSTRIDE + jt * 16 + m] = f2bf(acc[jt][r]);
    // same-wave DS ops are in-order; compiler inserts lgkmcnt waits
#pragma unroll
    for (int it = 0; it < 4; ++it) {
        int idx = it * 64 + lane;       // 0..255: 16 rows x 16 chunks of 16B
        int r = idx >> 4;
        int cb = idx & 15;
        int grow = row_base + r;
        if (grow < N) {
            short8 v = *(const short8*)&ob[r * WSTRIDE + cb * 8];
            *(short8*)(xlin + (size_t)grow * DIM + cb * 8) = v;
        }
    }
}

__device__ inline float4 bf4_to_f4(uint2 u) {
    float4 r;
    r.x = __builtin_bit_cast(float, u.x << 16);
    r.y = __builtin_bit_cast(float, u.x & 0xFFFF0000u);
    r.z = __builtin_bit_cast(float, u.y << 16);
    r.w = __builtin_bit_cast(float, u.y & 0xFFFF0000u);
    return r;
}

// 32 lanes per node, each owns 4 feature dims (8B bf16 loads). 8 nodes / 256-block.
__global__ __launch_bounds__(256) void aggregate(const unsigned short* __restrict__ xlin,
                                                 const int* __restrict__ bucket,
                                                 const int* __restrict__ deg,
                                                 const float* __restrict__ dinv,
                                                 const float* __restrict__ bias,
                                                 float* __restrict__ out, int N) {
    int node = blockIdx.x * 8 + (threadIdx.x >> 5);
    int lane = threadIdx.x & 31;
    if (node >= N) return;

    float di = dinv[node];
    int cnt = deg[node];
    if (cnt > CAP) cnt = CAP;

    const uint2* xl = (const uint2*)xlin;      // 4 bf16 per uint2
    float4 a = bf4_to_f4(xl[(size_t)node * 32 + lane]);   // self-loop message
    float4 acc = make_float4(di * a.x, di * a.y, di * a.z, di * a.w);

    const int* cl = bucket + (size_t)node * CAP;
    for (int i = 0; i < cnt; ++i) {
        int s = cl[i];                          // broadcast across 32 lanes
        float ds = dinv[s];
        float4 v = bf4_to_f4(xl[(size_t)s * 32 + lane]);  // 256B row gather
        acc.x = fmaf(ds, v.x, acc.x);
        acc.y = fmaf(ds, v.y, acc.y);
        acc.z = fmaf(ds, v.z, acc.z);
        acc.w = fmaf(ds, v.w, acc.w);
    }

    float4 bb = ((const float4*)bias)[lane];
    float4 o = make_float4(di * acc.x + bb.x, di * acc.y + bb.y,
                           di * acc.z + bb.z, di * acc.w + bb.w);
    ((float4*)out)[(size_t)node * 32 + lane] = o;
}

extern "C" void kernel_launch(void* const* d_in, const int* in_sizes, int n_in,
                              void* d_out, int out_size, void* d_ws, size_t ws_size,
                              hipStream_t stream) {
    const float* x    = (const float*)d_in[0];
    const int*   ei   = (const int*)d_in[1];
    const float* W    = (const float*)d_in[2];
    const float* bias = (const float*)d_in[3];
    float* out = (float*)d_out;

    const int N = in_sizes[0] / DIM;      // 100000
    const int E = in_sizes[1] / 2;        // 1600000

    // workspace: xlin(bf16) | deg | dinv | bucket
    char* ws = (char*)d_ws;
    size_t xlin_b = (size_t)N * DIM * 2;                  // 25.6 MB
    unsigned short* xlin = (unsigned short*)ws;
    int*   deg    = (int*)  (ws + xlin_b);
    float* dinv   = (float*)(ws + xlin_b + (size_t)N * 4);
    int*   bucket = (int*)  (ws + xlin_b + (size_t)N * 8); // 25.6 MB

    zero_deg<<<(N + 255) / 256, 256, 0, stream>>>(deg, N);
    fill_buckets<<<(E + 255) / 256, 256, 0, stream>>>(ei, E, deg, bucket);
    compute_dinv<<<(N + 255) / 256, 256, 0, stream>>>(deg, dinv, N);
    gemm_mfma<<<(N + 63) / 64, 256, 0, stream>>>(x, W, xlin, N);
    aggregate<<<(N + 7) / 8, 256, 0, stream>>>(xlin, bucket, deg, dinv, bias, out, N);
}

// Round 3
// 270.895 us; speedup vs baseline: 1.6147x; 1.2744x over previous
//
#include <hip/hip_runtime.h>
#include <hip/hip_bf16.h>

// GCNConv forward: out = D^-1/2 (A+I) D^-1/2 (x W^T) + b
// N=100000, E=1600000, DIM=128. fp32 in/out, edge_index as int32.
//
// R3: replace atomic bucket scatter (96MB random write-back, 1.6M device atomics)
// with a two-level binned CSR build: LDS histograms + block-private contiguous
// runs (P1) + per-bin L2-resident CSR scatter (P2). Exact CSR, no CAP limit.

#define DIM 128
#define BINSHIFT 9
#define BINSZ 512          // nodes per bin
#define MAXNB 256          // >= ceil(N/BINSZ) = 196
#define WSTRIDE 136        // shorts per LDS row in gemm: 16B-aligned, 2-way banks

typedef __attribute__((ext_vector_type(8))) short short8;
typedef __attribute__((ext_vector_type(4))) float f32x4;

__device__ inline unsigned short f2bf(float f) {
    unsigned u = __builtin_bit_cast(unsigned, f);
    return (unsigned short)((u + 0x7FFFu + ((u >> 16) & 1u)) >> 16);
}

__device__ inline float4 bf4_to_f4(uint2 u) {
    float4 r;
    r.x = __builtin_bit_cast(float, u.x << 16);
    r.y = __builtin_bit_cast(float, u.x & 0xFFFF0000u);
    r.z = __builtin_bit_cast(float, u.y << 16);
    r.w = __builtin_bit_cast(float, u.y & 0xFFFF0000u);
    return r;
}

// ---- CSR build pipeline ----------------------------------------------------

__global__ void zero_hist(int* __restrict__ hist) {
    hist[threadIdx.x] = 0;   // MAXNB == blockDim
}

// P0: per-block LDS histogram of dst bins, merged with one atomic per (block,bin)
__global__ __launch_bounds__(256) void bin_hist(const int* __restrict__ dst, int E,
                                                int* __restrict__ hist, int nb) {
    __shared__ int lh[MAXNB];
    int t = threadIdx.x;
    lh[t] = 0;
    __syncthreads();
    int chunk = (E + gridDim.x - 1) / gridDim.x;
    int base = blockIdx.x * chunk, end = min(E, base + chunk);
    for (int i = base + t; i < end; i += 256)
        atomicAdd(&lh[dst[i] >> BINSHIFT], 1);
    __syncthreads();
    if (t < nb && lh[t]) atomicAdd(&hist[t], lh[t]);
}

// exclusive scan of bin histogram (1 block, 256 threads, Hillis-Steele)
__global__ __launch_bounds__(256) void bin_scan(const int* __restrict__ hist,
                                                int* __restrict__ binStart,
                                                int* __restrict__ binCursor,
                                                int* __restrict__ row_ptr,
                                                int nb, int N) {
    __shared__ int sa[MAXNB], sb[MAXNB];
    int t = threadIdx.x;
    sa[t] = (t < nb) ? hist[t] : 0;
    __syncthreads();
    int* src = sa; int* dstp = sb;
    for (int step = 1; step < MAXNB; step <<= 1) {
        int v = src[t];
        if (t >= step) v += src[t - step];
        dstp[t] = v;
        __syncthreads();
        int* tmp = src; src = dstp; dstp = tmp;
    }
    if (t < nb) {
        int excl = src[t] - hist[t];
        binStart[t] = excl;
        binCursor[t] = excl;
    }
    if (t == nb - 1) binStart[nb] = src[t];   // == E
    if (t == 0) row_ptr[N] = src[nb - 1];     // == E
}

// P1: binned scatter. Two passes over a contiguous chunk: LDS hist -> one
// cursor atomic per bin -> block-private contiguous runs (coalesced write-back).
__global__ __launch_bounds__(256) void bin_scatter(const int* __restrict__ ei, int E,
                                                   int* __restrict__ binCursor,
                                                   int2* __restrict__ binned, int nb) {
    __shared__ int lh[MAXNB];
    __shared__ int lbase[MAXNB];
    int t = threadIdx.x;
    lh[t] = 0;
    __syncthreads();
    int chunk = (E + gridDim.x - 1) / gridDim.x;
    int base = blockIdx.x * chunk, end = min(E, base + chunk);
    for (int i = base + t; i < end; i += 256)
        atomicAdd(&lh[ei[E + i] >> BINSHIFT], 1);
    __syncthreads();
    if (t < nb) {
        int c = lh[t];
        lbase[t] = c ? atomicAdd(&binCursor[t], c) : 0;
        lh[t] = 0;
    }
    __syncthreads();
    for (int i = base + t; i < end; i += 256) {
        int s = ei[i], d = ei[E + i];
        int b = d >> BINSHIFT;
        int pos = lbase[b] + atomicAdd(&lh[b], 1);
        binned[pos] = make_int2(s, d);
    }
}

// P2: one block per bin. LDS degree count + scan -> row_ptr/dinv, then scatter
// src into exact CSR (writes confined to the bin's ~32KB L2-resident window).
__global__ __launch_bounds__(256) void csr_build(const int2* __restrict__ binned,
                                                 const int* __restrict__ binStart,
                                                 int* __restrict__ col,
                                                 int* __restrict__ row_ptr,
                                                 float* __restrict__ dinv, int N) {
    __shared__ int ldeg[BINSZ];
    __shared__ int sa[BINSZ], sb[BINSZ];
    __shared__ int lcur[BINSZ];
    int t = threadIdx.x, b = blockIdx.x;
    int s0 = binStart[b], s1 = binStart[b + 1];
    for (int i = t; i < BINSZ; i += 256) { ldeg[i] = 0; lcur[i] = 0; }
    __syncthreads();
    for (int i = s0 + t; i < s1; i += 256)
        atomicAdd(&ldeg[binned[i].y & (BINSZ - 1)], 1);
    __syncthreads();
    for (int i = t; i < BINSZ; i += 256) sa[i] = ldeg[i];
    __syncthreads();
    int* src = sa; int* dstp = sb;
    for (int step = 1; step < BINSZ; step <<= 1) {
        for (int i = t; i < BINSZ; i += 256) {
            int v = src[i];
            if (i >= step) v += src[i - step];
            dstp[i] = v;
        }
        __syncthreads();
        int* tmp = src; src = dstp; dstp = tmp;
    }
    // src = inclusive scan; exclusive into dstp
    for (int i = t; i < BINSZ; i += 256) dstp[i] = src[i] - ldeg[i];
    __syncthreads();
    for (int i = t; i < BINSZ; i += 256) {
        int n = (b << BINSHIFT) + i;
        if (n < N) {
            row_ptr[n] = s0 + dstp[i];
            dinv[n] = rsqrtf((float)(ldeg[i] + 1));   // +1 self loop
        }
    }
    for (int i = s0 + t; i < s1; i += 256) {
        int2 e = binned[i];
        int li = e.y & (BINSZ - 1);
        col[s0 + dstp[li] + atomicAdd(&lcur[li], 1)] = e.x;
    }
}

// ---- GEMM: xlin = bf16(x @ W.T) via 16x16x32 MFMA (unchanged from R2) ------

__global__ __launch_bounds__(256) void gemm_mfma(const float* __restrict__ x,
                                                 const float* __restrict__ W,
                                                 unsigned short* __restrict__ xlin, int N) {
    __shared__ unsigned short wbf[DIM * WSTRIDE];
    __shared__ unsigned short obuf[4 * 16 * WSTRIDE];
    int t = threadIdx.x;

    for (int it = 0; it < 16; ++it) {
        int f = it * 256 + t;
        int j = f >> 5;
        int kq = f & 31;
        float4 w4 = ((const float4*)W)[f];
        unsigned short* p = &wbf[j * WSTRIDE + kq * 4];
        p[0] = f2bf(w4.x); p[1] = f2bf(w4.y); p[2] = f2bf(w4.z); p[3] = f2bf(w4.w);
    }
    __syncthreads();

    int wid = t >> 6, lane = t & 63;
    int m = lane & 15, quad = lane >> 4;
    int row_base = blockIdx.x * 64 + wid * 16;

    f32x4 acc[8];
#pragma unroll
    for (int j = 0; j < 8; ++j) acc[j] = (f32x4){0.f, 0.f, 0.f, 0.f};

    int arow = row_base + m;
    if (arow >= N) arow = N - 1;
    const float* xr = x + (size_t)arow * DIM + quad * 8;

#pragma unroll
    for (int kc = 0; kc < 4; ++kc) {
        float4 a0 = *(const float4*)(xr + kc * 32);
        float4 a1 = *(const float4*)(xr + kc * 32 + 4);
        short8 af;
        af[0] = (short)f2bf(a0.x); af[1] = (short)f2bf(a0.y);
        af[2] = (short)f2bf(a0.z); af[3] = (short)f2bf(a0.w);
        af[4] = (short)f2bf(a1.x); af[5] = (short)f2bf(a1.y);
        af[6] = (short)f2bf(a1.z); af[7] = (short)f2bf(a1.w);
#pragma unroll
        for (int jt = 0; jt < 8; ++jt) {
            short8 bf = *(const short8*)&wbf[(jt * 16 + m) * WSTRIDE + kc * 32 + quad * 8];
            acc[jt] = __builtin_amdgcn_mfma_f32_16x16x32_bf16(af, bf, acc[jt], 0, 0, 0);
        }
    }

    unsigned short* ob = &obuf[wid * 16 * WSTRIDE];
#pragma unroll
    for (int jt = 0; jt < 8; ++jt)
#pragma unroll
        for (int r = 0; r < 4; ++r)
            ob[(quad * 4 + r) * WSTRIDE + jt * 16 + m] = f2bf(acc[jt][r]);
#pragma unroll
    for (int it = 0; it < 4; ++it) {
        int idx = it * 64 + lane;
        int r = idx >> 4;
        int cb = idx & 15;
        int grow = row_base + r;
        if (grow < N) {
            short8 v = *(const short8*)&ob[r * WSTRIDE + cb * 8];
            *(short8*)(xlin + (size_t)grow * DIM + cb * 8) = v;
        }
    }
}

// ---- Aggregate over CSR ----------------------------------------------------

__global__ __launch_bounds__(256) void aggregate(const unsigned short* __restrict__ xlin,
                                                 const int* __restrict__ col,
                                                 const int* __restrict__ row_ptr,
                                                 const float* __restrict__ dinv,
                                                 const float* __restrict__ bias,
                                                 float* __restrict__ out, int N) {
    int node = blockIdx.x * 8 + (threadIdx.x >> 5);
    int lane = threadIdx.x & 31;
    if (node >= N) return;

    float di = dinv[node];
    int r0 = row_ptr[node], r1 = row_ptr[node + 1];

    const uint2* xl = (const uint2*)xlin;
    float4 a = bf4_to_f4(xl[(size_t)node * 32 + lane]);   // self-loop message
    float4 acc = make_float4(di * a.x, di * a.y, di * a.z, di * a.w);

    for (int i = r0; i < r1; ++i) {
        int s = col[i];                         // broadcast across 32 lanes
        float ds = dinv[s];
        float4 v = bf4_to_f4(xl[(size_t)s * 32 + lane]);  // 256B row gather
        acc.x = fmaf(ds, v.x, acc.x);
        acc.y = fmaf(ds, v.y, acc.y);
        acc.z = fmaf(ds, v.z, acc.z);
        acc.w = fmaf(ds, v.w, acc.w);
    }

    float4 bb = ((const float4*)bias)[lane];
    float4 o = make_float4(di * acc.x + bb.x, di * acc.y + bb.y,
                           di * acc.z + bb.z, di * acc.w + bb.w);
    ((float4*)out)[(size_t)node * 32 + lane] = o;
}

// ---- launch ----------------------------------------------------------------

extern "C" void kernel_launch(void* const* d_in, const int* in_sizes, int n_in,
                              void* d_out, int out_size, void* d_ws, size_t ws_size,
                              hipStream_t stream) {
    const float* x    = (const float*)d_in[0];
    const int*   ei   = (const int*)d_in[1];
    const float* W    = (const float*)d_in[2];
    const float* bias = (const float*)d_in[3];
    float* out = (float*)d_out;

    const int N = in_sizes[0] / DIM;      // 100000
    const int E = in_sizes[1] / 2;        // 1600000
    const int nb = (N + BINSZ - 1) >> BINSHIFT;   // 196

    // workspace layout (256B-aligned slabs)
    char* ws = (char*)d_ws;
    size_t off = 0;
    auto alloc = [&](size_t bytes) { size_t o = off; off = (off + bytes + 255) & ~(size_t)255; return o; };
    unsigned short* xlin = (unsigned short*)(ws + alloc((size_t)N * DIM * 2)); // 25.6 MB
    int2* binned   = (int2*) (ws + alloc((size_t)E * 8));                      // 12.8 MB
    int*  col      = (int*)  (ws + alloc((size_t)E * 4));                      // 6.4 MB
    int*  row_ptr  = (int*)  (ws + alloc((size_t)(N + 1) * 4));
    float* dinv    = (float*)(ws + alloc((size_t)N * 4));
    int*  hist     = (int*)  (ws + alloc(MAXNB * 4));
    int*  binStart = (int*)  (ws + alloc((MAXNB + 1) * 4));
    int*  binCursor= (int*)  (ws + alloc(MAXNB * 4));

    zero_hist<<<1, MAXNB, 0, stream>>>(hist);
    bin_hist<<<256, 256, 0, stream>>>(ei + E, E, hist, nb);
    bin_scan<<<1, MAXNB, 0, stream>>>(hist, binStart, binCursor, row_ptr, nb, N);
    bin_scatter<<<256, 256, 0, stream>>>(ei, E, binCursor, binned, nb);
    csr_build<<<nb, 256, 0, stream>>>(binned, binStart, col, row_ptr, dinv, N);
    gemm_mfma<<<(N + 63) / 64, 256, 0, stream>>>(x, W, xlin, N);
    aggregate<<<(N + 7) / 8, 256, 0, stream>>>(xlin, col, row_ptr, dinv, bias, out, N);
}

// Round 4
// 232.475 us; speedup vs baseline: 1.8816x; 1.1653x over previous
//
#include <hip/hip_runtime.h>
#include <hip/hip_bf16.h>

// GCNConv forward: out = D^-1/2 (A+I) D^-1/2 (x W^T) + b
// N=100000, E=1600000, DIM=128. fp32 in/out, edge_index as int32.
//
// R4: aggregate re-tuned for memory-level parallelism (16 lanes/node, 16B bf16x8
// gathers, edge loop unrolled x4); gemm and bin_scatter fused into one kernel
// (scatter blocks first, LDS overlaid); zero_hist -> hipMemsetAsync.

#define DIM 128
#define BINSHIFT 9
#define BINSZ 512          // nodes per bin
#define MAXNB 256          // >= ceil(N/BINSZ) = 196
#define WSTRIDE 136        // shorts per LDS row in gemm: 16B-aligned, 2-way banks
#define SCAT_BLOCKS 256

typedef __attribute__((ext_vector_type(8))) short short8;
typedef __attribute__((ext_vector_type(4))) float f32x4;

__device__ inline unsigned short f2bf(float f) {
    unsigned u = __builtin_bit_cast(unsigned, f);
    return (unsigned short)((u + 0x7FFFu + ((u >> 16) & 1u)) >> 16);
}

// acc[j] += s * bf16_to_f32(row[j]) for 8 bf16 packed in a uint4
__device__ inline void bf8_axpy(uint4 v, float s, float* acc) {
    acc[0] = fmaf(s, __builtin_bit_cast(float, v.x << 16), acc[0]);
    acc[1] = fmaf(s, __builtin_bit_cast(float, v.x & 0xFFFF0000u), acc[1]);
    acc[2] = fmaf(s, __builtin_bit_cast(float, v.y << 16), acc[2]);
    acc[3] = fmaf(s, __builtin_bit_cast(float, v.y & 0xFFFF0000u), acc[3]);
    acc[4] = fmaf(s, __builtin_bit_cast(float, v.z << 16), acc[4]);
    acc[5] = fmaf(s, __builtin_bit_cast(float, v.z & 0xFFFF0000u), acc[5]);
    acc[6] = fmaf(s, __builtin_bit_cast(float, v.w << 16), acc[6]);
    acc[7] = fmaf(s, __builtin_bit_cast(float, v.w & 0xFFFF0000u), acc[7]);
}

// ---- CSR build pipeline ----------------------------------------------------

// P0: per-block LDS histogram of dst bins, merged with one atomic per (block,bin)
__global__ __launch_bounds__(256) void bin_hist(const int* __restrict__ dst, int E,
                                                int* __restrict__ hist, int nb) {
    __shared__ int lh[MAXNB];
    int t = threadIdx.x;
    lh[t] = 0;
    __syncthreads();
    int chunk = (E + gridDim.x - 1) / gridDim.x;
    int base = blockIdx.x * chunk, end = min(E, base + chunk);
    for (int i = base + t; i < end; i += 256)
        atomicAdd(&lh[dst[i] >> BINSHIFT], 1);
    __syncthreads();
    if (t < nb && lh[t]) atomicAdd(&hist[t], lh[t]);
}

// exclusive scan of bin histogram (1 block, 256 threads, Hillis-Steele)
__global__ __launch_bounds__(256) void bin_scan(const int* __restrict__ hist,
                                                int* __restrict__ binStart,
                                                int* __restrict__ binCursor,
                                                int* __restrict__ row_ptr,
                                                int nb, int N) {
    __shared__ int sa[MAXNB], sb[MAXNB];
    int t = threadIdx.x;
    sa[t] = (t < nb) ? hist[t] : 0;
    __syncthreads();
    int* src = sa; int* dstp = sb;
    for (int step = 1; step < MAXNB; step <<= 1) {
        int v = src[t];
        if (t >= step) v += src[t - step];
        dstp[t] = v;
        __syncthreads();
        int* tmp = src; src = dstp; dstp = tmp;
    }
    if (t < nb) {
        int excl = src[t] - hist[t];
        binStart[t] = excl;
        binCursor[t] = excl;
    }
    if (t == nb - 1) binStart[nb] = src[t];   // == E
    if (t == 0) row_ptr[N] = src[nb - 1];     // == E
}

// P2: one block per bin. LDS degree count + scan -> row_ptr/dinv, then scatter
// src into exact CSR (writes confined to the bin's ~32KB L2-resident window).
__global__ __launch_bounds__(256) void csr_build(const int2* __restrict__ binned,
                                                 const int* __restrict__ binStart,
                                                 int* __restrict__ col,
                                                 int* __restrict__ row_ptr,
                                                 float* __restrict__ dinv, int N) {
    __shared__ int ldeg[BINSZ];
    __shared__ int sa[BINSZ], sb[BINSZ];
    __shared__ int lcur[BINSZ];
    int t = threadIdx.x, b = blockIdx.x;
    int s0 = binStart[b], s1 = binStart[b + 1];
    for (int i = t; i < BINSZ; i += 256) { ldeg[i] = 0; lcur[i] = 0; }
    __syncthreads();
    for (int i = s0 + t; i < s1; i += 256)
        atomicAdd(&ldeg[binned[i].y & (BINSZ - 1)], 1);
    __syncthreads();
    for (int i = t; i < BINSZ; i += 256) sa[i] = ldeg[i];
    __syncthreads();
    int* src = sa; int* dstp = sb;
    for (int step = 1; step < BINSZ; step <<= 1) {
        for (int i = t; i < BINSZ; i += 256) {
            int v = src[i];
            if (i >= step) v += src[i - step];
            dstp[i] = v;
        }
        __syncthreads();
        int* tmp = src; src = dstp; dstp = tmp;
    }
    for (int i = t; i < BINSZ; i += 256) dstp[i] = src[i] - ldeg[i];  // exclusive
    __syncthreads();
    for (int i = t; i < BINSZ; i += 256) {
        int n = (b << BINSHIFT) + i;
        if (n < N) {
            row_ptr[n] = s0 + dstp[i];
            dinv[n] = rsqrtf((float)(ldeg[i] + 1));   // +1 self loop
        }
    }
    for (int i = s0 + t; i < s1; i += 256) {
        int2 e = binned[i];
        int li = e.y & (BINSZ - 1);
        col[s0 + dstp[li] + atomicAdd(&lcur[li], 1)] = e.x;
    }
}

// ---- Fused: bin_scatter (blocks 0..255) + MFMA gemm (blocks 256..) ---------

__global__ __launch_bounds__(256) void gemm_scatter(const float* __restrict__ x,
                                                    const float* __restrict__ W,
                                                    unsigned short* __restrict__ xlin, int N,
                                                    const int* __restrict__ ei, int E,
                                                    int* __restrict__ binCursor,
                                                    int2* __restrict__ binned, int nb) {
    __shared__ unsigned short wbf[DIM * WSTRIDE];       // gemm W tile / scatter hists
    __shared__ unsigned short obuf[4 * 16 * WSTRIDE];
    int t = threadIdx.x;

    if (blockIdx.x < SCAT_BLOCKS) {
        // ---- scatter role: LDS hist -> one cursor atomic/bin -> contiguous runs
        int* lh = (int*)wbf;
        int* lbase = lh + MAXNB;
        lh[t] = 0;
        __syncthreads();
        int chunk = (E + SCAT_BLOCKS - 1) / SCAT_BLOCKS;
        int base = blockIdx.x * chunk, end = min(E, base + chunk);
        for (int i = base + t; i < end; i += 256)
            atomicAdd(&lh[ei[E + i] >> BINSHIFT], 1);
        __syncthreads();
        if (t < nb) {
            int c = lh[t];
            lbase[t] = c ? atomicAdd(&binCursor[t], c) : 0;
            lh[t] = 0;
        }
        __syncthreads();
        for (int i = base + t; i < end; i += 256) {
            int s = ei[i], d = ei[E + i];
            int b = d >> BINSHIFT;
            int pos = lbase[b] + atomicAdd(&lh[b], 1);
            binned[pos] = make_int2(s, d);
        }
        return;
    }

    // ---- gemm role: xlin = bf16(x @ W.T), 16x16x32 MFMA
    for (int it = 0; it < 16; ++it) {
        int f = it * 256 + t;
        int j = f >> 5;
        int kq = f & 31;
        float4 w4 = ((const float4*)W)[f];
        unsigned short* p = &wbf[j * WSTRIDE + kq * 4];
        p[0] = f2bf(w4.x); p[1] = f2bf(w4.y); p[2] = f2bf(w4.z); p[3] = f2bf(w4.w);
    }
    __syncthreads();

    int wid = t >> 6, lane = t & 63;
    int m = lane & 15, quad = lane >> 4;
    int row_base = (blockIdx.x - SCAT_BLOCKS) * 64 + wid * 16;

    f32x4 acc[8];
#pragma unroll
    for (int j = 0; j < 8; ++j) acc[j] = (f32x4){0.f, 0.f, 0.f, 0.f};

    int arow = row_base + m;
    if (arow >= N) arow = N - 1;
    const float* xr = x + (size_t)arow * DIM + quad * 8;

#pragma unroll
    for (int kc = 0; kc < 4; ++kc) {
        float4 a0 = *(const float4*)(xr + kc * 32);
        float4 a1 = *(const float4*)(xr + kc * 32 + 4);
        short8 af;
        af[0] = (short)f2bf(a0.x); af[1] = (short)f2bf(a0.y);
        af[2] = (short)f2bf(a0.z); af[3] = (short)f2bf(a0.w);
        af[4] = (short)f2bf(a1.x); af[5] = (short)f2bf(a1.y);
        af[6] = (short)f2bf(a1.z); af[7] = (short)f2bf(a1.w);
#pragma unroll
        for (int jt = 0; jt < 8; ++jt) {
            short8 bf = *(const short8*)&wbf[(jt * 16 + m) * WSTRIDE + kc * 32 + quad * 8];
            acc[jt] = __builtin_amdgcn_mfma_f32_16x16x32_bf16(af, bf, acc[jt], 0, 0, 0);
        }
    }

    unsigned short* ob = &obuf[wid * 16 * WSTRIDE];
#pragma unroll
    for (int jt = 0; jt < 8; ++jt)
#pragma unroll
        for (int r = 0; r < 4; ++r)
            ob[(quad * 4 + r) * WSTRIDE + jt * 16 + m] = f2bf(acc[jt][r]);
#pragma unroll
    for (int it = 0; it < 4; ++it) {
        int idx = it * 64 + lane;
        int r = idx >> 4;
        int cb = idx & 15;
        int grow = row_base + r;
        if (grow < N) {
            short8 v = *(const short8*)&ob[r * WSTRIDE + cb * 8];
            *(short8*)(xlin + (size_t)grow * DIM + cb * 8) = v;
        }
    }
}

// ---- Aggregate over CSR: 16 lanes/node, bf16x8 gathers, unroll x4 ----------

__global__ __launch_bounds__(256) void aggregate(const unsigned short* __restrict__ xlin,
                                                 const int* __restrict__ col,
                                                 const int* __restrict__ row_ptr,
                                                 const float* __restrict__ dinv,
                                                 const float* __restrict__ bias,
                                                 float* __restrict__ out, int N) {
    int node = blockIdx.x * 16 + (threadIdx.x >> 4);
    int lane = threadIdx.x & 15;          // owns dims 8*lane .. 8*lane+7
    if (node >= N) return;

    float di = dinv[node];
    int r0 = row_ptr[node], r1 = row_ptr[node + 1];

    const uint4* xl = (const uint4*)xlin;     // 8 bf16 per uint4; 16 uint4 per row
    float acc[8] = {};
    bf8_axpy(xl[(size_t)node * 16 + lane], di, acc);   // self-loop message

    int i = r0;
    for (; i + 4 <= r1; i += 4) {
        int s0 = col[i], s1 = col[i + 1], s2 = col[i + 2], s3 = col[i + 3];
        float d0 = dinv[s0], d1 = dinv[s1], d2 = dinv[s2], d3 = dinv[s3];
        uint4 v0 = xl[(size_t)s0 * 16 + lane];
        uint4 v1 = xl[(size_t)s1 * 16 + lane];
        uint4 v2 = xl[(size_t)s2 * 16 + lane];
        uint4 v3 = xl[(size_t)s3 * 16 + lane];
        bf8_axpy(v0, d0, acc);
        bf8_axpy(v1, d1, acc);
        bf8_axpy(v2, d2, acc);
        bf8_axpy(v3, d3, acc);
    }
    for (; i < r1; ++i) {
        int s = col[i];
        bf8_axpy(xl[(size_t)s * 16 + lane], dinv[s], acc);
    }

    const float4* b4 = (const float4*)(bias + lane * 8);
    float4 bl = b4[0], bh = b4[1];
    float4 olo = make_float4(di * acc[0] + bl.x, di * acc[1] + bl.y,
                             di * acc[2] + bl.z, di * acc[3] + bl.w);
    float4 ohi = make_float4(di * acc[4] + bh.x, di * acc[5] + bh.y,
                             di * acc[6] + bh.z, di * acc[7] + bh.w);
    float4* op = (float4*)(out + (size_t)node * DIM + lane * 8);
    op[0] = olo;
    op[1] = ohi;
}

// ---- launch ----------------------------------------------------------------

extern "C" void kernel_launch(void* const* d_in, const int* in_sizes, int n_in,
                              void* d_out, int out_size, void* d_ws, size_t ws_size,
                              hipStream_t stream) {
    const float* x    = (const float*)d_in[0];
    const int*   ei   = (const int*)d_in[1];
    const float* W    = (const float*)d_in[2];
    const float* bias = (const float*)d_in[3];
    float* out = (float*)d_out;

    const int N = in_sizes[0] / DIM;      // 100000
    const int E = in_sizes[1] / 2;        // 1600000
    const int nb = (N + BINSZ - 1) >> BINSHIFT;   // 196

    char* ws = (char*)d_ws;
    size_t off = 0;
    auto alloc = [&](size_t bytes) { size_t o = off; off = (off + bytes + 255) & ~(size_t)255; return o; };
    unsigned short* xlin = (unsigned short*)(ws + alloc((size_t)N * DIM * 2)); // 25.6 MB
    int2* binned   = (int2*) (ws + alloc((size_t)E * 8));                      // 12.8 MB
    int*  col      = (int*)  (ws + alloc((size_t)E * 4));                      // 6.4 MB
    int*  row_ptr  = (int*)  (ws + alloc((size_t)(N + 1) * 4));
    float* dinv    = (float*)(ws + alloc((size_t)N * 4));
    int*  hist     = (int*)  (ws + alloc(MAXNB * 4));
    int*  binStart = (int*)  (ws + alloc((MAXNB + 1) * 4));
    int*  binCursor= (int*)  (ws + alloc(MAXNB * 4));

    hipMemsetAsync(hist, 0, MAXNB * 4, stream);
    bin_hist<<<256, 256, 0, stream>>>(ei + E, E, hist, nb);
    bin_scan<<<1, MAXNB, 0, stream>>>(hist, binStart, binCursor, row_ptr, nb, N);
    gemm_scatter<<<SCAT_BLOCKS + (N + 63) / 64, 256, 0, stream>>>(
        x, W, xlin, N, ei, E, binCursor, binned, nb);
    csr_build<<<nb, 256, 0, stream>>>(binned, binStart, col, row_ptr, dinv, N);
    aggregate<<<(N + 15) / 16, 256, 0, stream>>>(xlin, col, row_ptr, dinv, bias, out, N);
}